// Round 5
// baseline (30.718 us; speedup 1.0000x reference)
//
#include <hip/hip_runtime.h>

// CASSI base-mode forward on MI355X (gfx950).
// x:  (1, 31, 1024, 1024) f32, ca: (1, 1, 1024, 1024) f32
// out: (1, 1, 1024, 1054) f32
//
// Round-5: aligned "scatter-in-registers" formulation. N == 4*256, so one
// 256-thread block owns a full output row m; thread t owns x columns
// 4t..4t+3. Every x/ca load is an aligned global_load_dwordx4 (1KB per wave
// per instruction, no sector straddle) — 4x fewer VMEM instructions than the
// shifted scalar gather of rounds 2/4. The prism shear lives entirely in a
// per-thread acc[34] register file: acc[l+j] += x[l][m][4t+j]*ca[m][4t+j]
// (indices compile-time after full unroll). ca is read ONCE per thread from
// global (4MB, L3-resident) — no LDS and no barrier in the main loop.
// Epilogue: one LDS round-trip (stride 35 dwords -> <=2-way banks, free) and
// a <=9-term reduction per output column. No zero-padding, no halo: x col n
// contributes to out cols n..n+30, which tile [0,1054) exactly.

constexpr int L = 31;
constexpr int M = 1024;
constexpr int N = 1024;
constexpr int NC = N + L - 1;            // 1054 output columns
constexpr int LSTRIDE = M * N;           // elements between successive l-slices
constexpr int BLK = 256;
constexpr int ACCW = 4 + (L - 1);        // 34 accumulators per thread
constexpr int PAD = 35;                  // LDS row stride (odd -> 2-way max)

typedef float f32x4 __attribute__((ext_vector_type(4)));

__global__ __launch_bounds__(BLK, 4) void cassi_fwd_kernel(
    const float* __restrict__ x,
    const float* __restrict__ ca,
    float* __restrict__ out)
{
    __shared__ float red[BLK * PAD];      // 35,840 B -> 4 blocks/CU

    const int t = threadIdx.x;
    const int m = blockIdx.x;             // output row

    // ca for this thread's 4 columns: one aligned 16B load, reused for all taps.
    f32x4 cav;
    __builtin_memcpy(&cav, ca + m * N + 4 * t, 16);

    float acc[ACCW];
#pragma unroll
    for (int k = 0; k < ACCW; ++k) acc[k] = 0.0f;

    // Main loop: 31 aligned dwordx4 loads, 124 FMAs, zero LDS, zero barriers.
    const float* xp = x + m * N + 4 * t;
#pragma unroll
    for (int l = 0; l < L; ++l) {
        f32x4 q;
        __builtin_memcpy(&q, xp + (long)l * LSTRIDE, 16);
#pragma unroll
        for (int j = 0; j < 4; ++j)
            acc[l + j] = fmaf(q[j], cav[j], acc[l + j]);
    }

    // Epilogue: park acc in LDS, then reduce the <=9 overlapping windows.
#pragma unroll
    for (int k = 0; k < ACCW; ++k) red[t * PAD + k] = acc[k];
    __syncthreads();

    for (int c = t; c < NC; c += BLK) {
        // out[m][c] = sum over threads tt with 0 <= c-4tt <= 33.
        int tlo = (c - 30) >> 2;          // ceil((c-33)/4), arith shift = floor
        if (tlo < 0) tlo = 0;
        int thi = c >> 2;
        if (thi > BLK - 1) thi = BLK - 1;
        float s = 0.0f;
        for (int tt = tlo; tt <= thi; ++tt)
            s += red[tt * PAD + (c - 4 * tt)];
        out[(long)m * NC + c] = s;
    }
}

extern "C" void kernel_launch(void* const* d_in, const int* in_sizes, int n_in,
                              void* d_out, int out_size, void* d_ws, size_t ws_size,
                              hipStream_t stream)
{
    const float* x  = (const float*)d_in[0];
    const float* ca = (const float*)d_in[1];
    float* out = (float*)d_out;

    dim3 block(BLK, 1, 1);
    dim3 grid(M, 1, 1);                   // 1024 blocks, one per output row
    cassi_fwd_kernel<<<grid, block, 0, stream>>>(x, ca, out);
}

// Round 6
// 25.469 us; speedup vs baseline: 1.2061x; 1.2061x over previous
//
#include <hip/hip_runtime.h>

// CASSI base-mode forward on MI355X (gfx950).
// x:  (1, 31, 1024, 1024) f32, ca: (1, 1, 1024, 1024) f32
// out: (1, 1, 1024, 1054) f32
// Gather: out[m][c] = sum_l x[l][m][c-l] * ca[m][c-l]; each x element is
// touched exactly once (tap l selects slice l) -> compulsory ~138 MB.
//
// Round-6 = round-2 (best: 28.8us) + the last two mechanism-backed knobs:
//  (1) __launch_bounds__(256,8): cap VGPR at 64 -> 32 waves/CU (2x load
//      concurrency; R2's VGPR count was never observed and a 31-deep load
//      pipeline plausibly exceeded 128 -> 16 waves/CU, same as all variants).
//  (2) bijective XCD-chunked block swizzle: same-row neighbor blocks (shared
//      ca halo + straddled 64B boundary lines) land on the SAME XCD's L2.
//  (3) divergence-free main loop: clamp tail columns for loads, predicate
//      only the final store.

constexpr int L = 31;
constexpr int M = 1024;
constexpr int N = 1024;
constexpr int NC = N + L - 1;            // 1054 output columns
constexpr int LSTRIDE = M * N;           // elements between successive l-slices
constexpr int BLK = 256;
constexpr int HALO = L - 1;              // 30
constexpr int CA_TILE = BLK + HALO;      // 286 staged ca columns
constexpr int GX = (NC + BLK - 1) / BLK; // 5 column-blocks per row
constexpr int NWG = GX * M;              // 5120 workgroups (== 0 mod 8)
constexpr int NXCD = 8;
constexpr int QX = NWG / NXCD;           // 640

__global__ __launch_bounds__(BLK, 8) void cassi_fwd_kernel(
    const float* __restrict__ x,
    const float* __restrict__ ca,
    float* __restrict__ out)
{
    __shared__ float sca[CA_TILE];

    // XCD-chunked swizzle (bijective since NWG % 8 == 0): launched blocks
    // with the same (orig & 7) share an XCD under round-robin dispatch; give
    // each XCD a contiguous logical chunk so same-row neighbors share L2.
    const int orig = blockIdx.x;
    const int wg   = (orig & 7) * QX + (orig >> 3);
    const int m    = wg / GX;
    const int bx   = wg - m * GX;
    const int C0   = bx * BLK;
    const int tid  = threadIdx.x;

    // Stage ca[m][C0-30 .. C0+255] into LDS, zero-padded outside [0,N).
    for (int i = tid; i < CA_TILE; i += BLK) {
        const int col = C0 - HALO + i;
        sca[i] = ((unsigned)col < (unsigned)N) ? ca[m * N + col] : 0.0f;
    }
    __syncthreads();

    const int c  = C0 + tid;
    const int cw = (c < NC) ? tid : (NC - 1 - C0);   // clamped in-block col
    const float* xp = x + m * N + C0 + cw;

    // All 31 tap offsets proven in-bounds: max index (l=30,m=1023,c=1053)
    // = 31*2^20 - 1; min (l>=1, c<l) >= 2^20 - 30 > 0 (pad value * 0.0).
    float acc = 0.0f;
#pragma unroll
    for (int l = 0; l < L; ++l) {
        acc = fmaf(xp[l * LSTRIDE - l], sca[cw + HALO - l], acc);
    }

    if (c < NC) out[m * NC + c] = acc;
}

extern "C" void kernel_launch(void* const* d_in, const int* in_sizes, int n_in,
                              void* d_out, int out_size, void* d_ws, size_t ws_size,
                              hipStream_t stream)
{
    const float* x  = (const float*)d_in[0];
    const float* ca = (const float*)d_in[1];
    float* out = (float*)d_out;

    dim3 block(BLK, 1, 1);
    dim3 grid(NWG, 1, 1);                 // 5120 blocks, 1-D for the swizzle
    cassi_fwd_kernel<<<grid, block, 0, stream>>>(x, ca, out);
}